// Round 1
// baseline (517.829 us; speedup 1.0000x reference)
//
#include <hip/hip_runtime.h>

#define E_DIM 512
#define U_DIM 64
#define T_DIM 8
#define A_DIM 32
#define NB    10
#define BATCH 8192
#define WPB   4   // waves (batch elements) per block

// One batch element per wave: no __syncthreads anywhere.
// Cross-lane traffic inside a wave uses per-wave LDS slabs (intra-wave DS ops
// complete in order on CDNA; wave_barrier() pins compiler ordering) + shuffles.
__launch_bounds__(256, 4)
__global__ void gatne_kernel(
    const float* __restrict__ node_embeddings,      // [N, 512]
    const float* __restrict__ node_type_embeddings, // [N, 8, 64]
    const float* __restrict__ trans_weights,        // [8, 64, 512]
    const float* __restrict__ trans_weights_s1,     // [8, 64, 32]
    const float* __restrict__ trans_weights_s2,     // [8, 32]
    const int*   __restrict__ train_inputs,         // [B]
    const int*   __restrict__ train_types,          // [B]
    const int*   __restrict__ node_neigh,           // [B, 8, 10]
    float*       __restrict__ out)                  // [B, 512]
{
    const int tid  = threadIdx.x;
    const int lane = tid & 63;
    const int wv   = tid >> 6;
    const int b    = blockIdx.x * WPB + wv;

    __shared__ float s_nte[WPB][T_DIM][U_DIM];   // 8 KB
    __shared__ float s_agg[WPB][U_DIM];          // 1 KB

    const int ni = train_inputs[b];
    const int ty = train_types[b];

    // ---- prefetch node_embed row early: 8 consecutive floats per lane ----
    const float* neb = node_embeddings + (size_t)ni * E_DIM + lane * 8;
    const float4 ne0 = *(const float4*)(neb);
    const float4 ne1 = *(const float4*)(neb + 4);

    // ---- neighbor indices into registers (80 ints per wave) ----
    const int* nn = node_neigh + (size_t)b * (T_DIM * NB);
    const int idx0 = nn[lane];                                  // lanes 0..63
    const int idx1 = (lane < (T_DIM * NB - 64)) ? nn[64 + lane] : 0;  // lanes 0..15

    // ---- gather + neighbor-sum: acc[t] = sum_n nte[neigh[t,n], t, lane] ----
    float acc[T_DIM];
    #pragma unroll
    for (int t = 0; t < T_DIM; ++t) {
        float a = 0.f;
        #pragma unroll
        for (int n = 0; n < NB; ++n) {
            const int j = t * NB + n;
            const int nbi = (j < 64) ? __shfl(idx0, j, 64)
                                     : __shfl(idx1, j - 64, 64);
            a += node_type_embeddings[(size_t)nbi * (T_DIM * U_DIM) + t * U_DIM + lane];
        }
        acc[t] = a;
        s_nte[wv][t][lane] = a;
    }
    __builtin_amdgcn_wave_barrier();   // writes above visible to reads below (intra-wave)

    // ---- attention: lane (half = lane>>5, a = lane&31) computes t = half + 2k ----
    const int a_idx = lane & 31;
    const int half  = lane >> 5;
    const float* w1 = trans_weights_s1 + (size_t)ty * (U_DIM * A_DIM) + a_idx;
    float h0 = 0.f, h1 = 0.f, h2 = 0.f, h3 = 0.f;
    #pragma unroll
    for (int u = 0; u < U_DIM; ++u) {
        const float wv1 = w1[u * A_DIM];                 // L1/L2-hot, 128B/wave/iter
        h0 = fmaf(s_nte[wv][half + 0][u], wv1, h0);
        h1 = fmaf(s_nte[wv][half + 2][u], wv1, h1);
        h2 = fmaf(s_nte[wv][half + 4][u], wv1, h2);
        h3 = fmaf(s_nte[wv][half + 6][u], wv1, h3);
    }
    const float w2v = trans_weights_s2[ty * A_DIM + a_idx];
    h0 = tanhf(h0) * w2v;
    h1 = tanhf(h1) * w2v;
    h2 = tanhf(h2) * w2v;
    h3 = tanhf(h3) * w2v;
    #pragma unroll
    for (int off = 16; off > 0; off >>= 1) {             // reduce over a within each half
        h0 += __shfl_down(h0, off, 32);
        h1 += __shfl_down(h1, off, 32);
        h2 += __shfl_down(h2, off, 32);
        h3 += __shfl_down(h3, off, 32);
    }
    // lane 0 holds scores for t=0,2,4,6 ; lane 32 holds t=1,3,5,7 → broadcast all 8
    const float s0 = __shfl(h0, 0, 64),  s2 = __shfl(h1, 0, 64);
    const float s4 = __shfl(h2, 0, 64),  s6 = __shfl(h3, 0, 64);
    const float s1 = __shfl(h0, 32, 64), s3 = __shfl(h1, 32, 64);
    const float s5 = __shfl(h2, 32, 64), s7 = __shfl(h3, 32, 64);

    // ---- softmax over 8 types, redundantly per lane (pure VALU) ----
    const float m = fmaxf(fmaxf(fmaxf(s0, s1), fmaxf(s2, s3)),
                          fmaxf(fmaxf(s4, s5), fmaxf(s6, s7)));
    const float e0 = __expf(s0 - m), e1 = __expf(s1 - m);
    const float e2 = __expf(s2 - m), e3 = __expf(s3 - m);
    const float e4 = __expf(s4 - m), e5 = __expf(s5 - m);
    const float e6 = __expf(s6 - m), e7 = __expf(s7 - m);
    const float inv_sum = 1.f / (e0 + e1 + e2 + e3 + e4 + e5 + e6 + e7);

    // ---- agg[u=lane] straight from the register accumulators ----
    const float agg = (e0 * acc[0] + e1 * acc[1] + e2 * acc[2] + e3 * acc[3] +
                       e4 * acc[4] + e5 * acc[5] + e6 * acc[6] + e7 * acc[7]) * inv_sum;
    s_agg[wv][lane] = agg;
    __builtin_amdgcn_wave_barrier();

    // ---- out[e] = node_embed[e] + sum_u agg[u] * w[ty,u,e], e = lane*8 .. +7 ----
    const float* wb = trans_weights + (size_t)ty * (U_DIM * E_DIM) + lane * 8;
    float4 v0 = ne0, v1 = ne1;
    #pragma unroll 8
    for (int u = 0; u < U_DIM; ++u) {
        const float av = s_agg[wv][u];                   // LDS broadcast
        const float4 w0  = *(const float4*)(wb + (size_t)u * E_DIM);
        const float4 w1v = *(const float4*)(wb + (size_t)u * E_DIM + 4);
        v0.x = fmaf(av, w0.x, v0.x);  v0.y = fmaf(av, w0.y, v0.y);
        v0.z = fmaf(av, w0.z, v0.z);  v0.w = fmaf(av, w0.w, v0.w);
        v1.x = fmaf(av, w1v.x, v1.x); v1.y = fmaf(av, w1v.y, v1.y);
        v1.z = fmaf(av, w1v.z, v1.z); v1.w = fmaf(av, w1v.w, v1.w);
    }

    // ---- L2 norm via shfl_xor butterfly (all lanes end with the total) ----
    float ss = v0.x * v0.x + v0.y * v0.y + v0.z * v0.z + v0.w * v0.w
             + v1.x * v1.x + v1.y * v1.y + v1.z * v1.z + v1.w * v1.w;
    #pragma unroll
    for (int off = 32; off > 0; off >>= 1)
        ss += __shfl_xor(ss, off, 64);
    const float inv = 1.f / fmaxf(sqrtf(ss), 1e-12f);

    float4 o0, o1;
    o0.x = v0.x * inv; o0.y = v0.y * inv; o0.z = v0.z * inv; o0.w = v0.w * inv;
    o1.x = v1.x * inv; o1.y = v1.y * inv; o1.z = v1.z * inv; o1.w = v1.w * inv;
    float* ob = out + (size_t)b * E_DIM + lane * 8;
    *(float4*)(ob)     = o0;
    *(float4*)(ob + 4) = o1;
}

extern "C" void kernel_launch(void* const* d_in, const int* in_sizes, int n_in,
                              void* d_out, int out_size, void* d_ws, size_t ws_size,
                              hipStream_t stream) {
    const float* node_embeddings      = (const float*)d_in[0];
    const float* node_type_embeddings = (const float*)d_in[1];
    const float* trans_weights        = (const float*)d_in[2];
    const float* trans_weights_s1     = (const float*)d_in[3];
    const float* trans_weights_s2     = (const float*)d_in[4];
    const int*   train_inputs         = (const int*)d_in[5];
    const int*   train_types          = (const int*)d_in[6];
    const int*   node_neigh           = (const int*)d_in[7];
    float* out = (float*)d_out;

    gatne_kernel<<<BATCH / WPB, 256, 0, stream>>>(
        node_embeddings, node_type_embeddings, trans_weights,
        trans_weights_s1, trans_weights_s2,
        train_inputs, train_types, node_neigh, out);
}

// Round 2
// 416.692 us; speedup vs baseline: 1.2427x; 1.2427x over previous
//
#include <hip/hip_runtime.h>

#define E_DIM 512
#define U_DIM 64
#define T_DIM 8
#define A_DIM 32
#define NB    10
#define BATCH 8192

// Block per batch element (8192 blocks), 256 threads = 4 waves.
// __launch_bounds__(256,8): cap VGPR at 64 -> 8 blocks/CU resident (32 waves/CU)
// for latency hiding of the random 256B gathers. LDS kept tiny (~2.3 KB) by
// reading w1/w2 straight from global (L2-hot: 8KB + 128B unique per block).
__launch_bounds__(256, 8)
__global__ void gatne_kernel(
    const float* __restrict__ node_embeddings,      // [N, 512]
    const float* __restrict__ node_type_embeddings, // [N, 8, 64]
    const float* __restrict__ trans_weights,        // [8, 64, 512]
    const float* __restrict__ trans_weights_s1,     // [8, 64, 32]
    const float* __restrict__ trans_weights_s2,     // [8, 32]
    const int*   __restrict__ train_inputs,         // [B]
    const int*   __restrict__ train_types,          // [B]
    const int*   __restrict__ node_neigh,           // [B, 8, 10]
    float*       __restrict__ out)                  // [B, 512]
{
    const int b    = blockIdx.x;
    const int tid  = threadIdx.x;
    const int lane = tid & 63;
    const int wv   = tid >> 6;     // wave 0..3 handles types wv and wv+4

    __shared__ float s_nte[T_DIM][U_DIM];   // 2 KB
    __shared__ float s_att[T_DIM];
    __shared__ float s_agg[U_DIM];
    __shared__ float s_red[4];

    // ---- per-wave neighbor indices via shfl broadcast (no LDS, no barrier) ----
    // lanes 0..9  -> row t=wv   : nn[wv*10 + lane]
    // lanes 10..19-> row t=wv+4 : nn[(wv+4)*10 + (lane-10)] = nn[wv*10 + 30 + lane]
    const int* nn = node_neigh + (size_t)b * (T_DIM * NB);
    int my = 0;
    if (lane < 2 * NB) my = nn[wv * NB + (lane < NB ? lane : 30 + lane)];

    const int ni = train_inputs[b];   // block-uniform -> scalar loads
    const int ty = train_types[b];

    // ---- prefetch node_embed row early (2 floats per thread, coalesced) ----
    const int e0 = tid * 2;
    const float2 ne = *(const float2*)(node_embeddings + (size_t)ni * E_DIM + e0);

    // ---- gather + neighbor-sum: wave wv does types wv and wv+4 ----
    float a0 = 0.f, a1 = 0.f;
    #pragma unroll
    for (int n = 0; n < NB; ++n) {
        const int i0 = __shfl(my, n, 64);
        const int i1 = __shfl(my, NB + n, 64);
        a0 += node_type_embeddings[(size_t)i0 * (T_DIM * U_DIM) + wv * U_DIM + lane];
        a1 += node_type_embeddings[(size_t)i1 * (T_DIM * U_DIM) + (wv + 4) * U_DIM + lane];
    }
    s_nte[wv][lane]     = a0;
    s_nte[wv + 4][lane] = a1;
    __syncthreads();

    // ---- attention scores: thread (t = tid>>5, a = tid&31) ----
    {
        const int t = tid >> 5;
        const int a = tid & 31;
        const float* w1 = trans_weights_s1 + (size_t)ty * (U_DIM * A_DIM) + a;
        float h = 0.f;
        #pragma unroll
        for (int u = 0; u < U_DIM; ++u)
            h = fmaf(s_nte[t][u], w1[u * A_DIM], h);   // LDS broadcast * L2-hot 128B
        float val = tanhf(h) * trans_weights_s2[ty * A_DIM + a];
        #pragma unroll
        for (int off = 16; off > 0; off >>= 1)
            val += __shfl_down(val, off, 32);
        if (a == 0) s_att[t] = val;                    // raw score
    }
    __syncthreads();

    // ---- softmax (redundant, in-register) fused with agg: threads 0..63 ----
    if (tid < U_DIM) {
        float sc0 = s_att[0], sc1 = s_att[1], sc2 = s_att[2], sc3 = s_att[3];
        float sc4 = s_att[4], sc5 = s_att[5], sc6 = s_att[6], sc7 = s_att[7];
        const float m = fmaxf(fmaxf(fmaxf(sc0, sc1), fmaxf(sc2, sc3)),
                              fmaxf(fmaxf(sc4, sc5), fmaxf(sc6, sc7)));
        const float x0 = __expf(sc0 - m), x1 = __expf(sc1 - m);
        const float x2 = __expf(sc2 - m), x3 = __expf(sc3 - m);
        const float x4 = __expf(sc4 - m), x5 = __expf(sc5 - m);
        const float x6 = __expf(sc6 - m), x7 = __expf(sc7 - m);
        const float inv_sum = 1.f / (x0 + x1 + x2 + x3 + x4 + x5 + x6 + x7);
        const float acc = x0 * s_nte[0][tid] + x1 * s_nte[1][tid]
                        + x2 * s_nte[2][tid] + x3 * s_nte[3][tid]
                        + x4 * s_nte[4][tid] + x5 * s_nte[5][tid]
                        + x6 * s_nte[6][tid] + x7 * s_nte[7][tid];
        s_agg[tid] = acc * inv_sum;
    }
    __syncthreads();

    // ---- out[e] = node_embed[e] + sum_u agg[u] * w[ty,u,e] ----
    const float* wb = trans_weights + (size_t)ty * (U_DIM * E_DIM) + e0;
    float v0 = ne.x, v1 = ne.y;
    #pragma unroll 16
    for (int u = 0; u < U_DIM; ++u) {
        const float av = s_agg[u];                     // LDS broadcast
        const float2 w2v = *(const float2*)(wb + (size_t)u * E_DIM);
        v0 = fmaf(av, w2v.x, v0);
        v1 = fmaf(av, w2v.y, v1);
    }

    // ---- block L2-norm: wave butterfly + 4-entry LDS combine ----
    float ss = v0 * v0 + v1 * v1;
    #pragma unroll
    for (int off = 32; off > 0; off >>= 1)
        ss += __shfl_xor(ss, off, 64);
    if (lane == 0) s_red[wv] = ss;
    __syncthreads();
    const float total = s_red[0] + s_red[1] + s_red[2] + s_red[3];
    const float inv = 1.f / fmaxf(sqrtf(total), 1e-12f);

    float2 o; o.x = v0 * inv; o.y = v1 * inv;
    *(float2*)(out + (size_t)b * E_DIM + e0) = o;
}

extern "C" void kernel_launch(void* const* d_in, const int* in_sizes, int n_in,
                              void* d_out, int out_size, void* d_ws, size_t ws_size,
                              hipStream_t stream) {
    const float* node_embeddings      = (const float*)d_in[0];
    const float* node_type_embeddings = (const float*)d_in[1];
    const float* trans_weights        = (const float*)d_in[2];
    const float* trans_weights_s1     = (const float*)d_in[3];
    const float* trans_weights_s2     = (const float*)d_in[4];
    const int*   train_inputs         = (const int*)d_in[5];
    const int*   train_types          = (const int*)d_in[6];
    const int*   node_neigh           = (const int*)d_in[7];
    float* out = (float*)d_out;

    gatne_kernel<<<BATCH, 256, 0, stream>>>(
        node_embeddings, node_type_embeddings, trans_weights,
        trans_weights_s1, trans_weights_s2,
        train_inputs, train_types, node_neigh, out);
}